// Round 11
// baseline (81.420 us; speedup 1.0000x reference)
//
#include <hip/hip_runtime.h>

// Problem constants (fixed by setup_inputs): B=4, T=28, N=1024, D=3
constexpr int Bc = 4;
constexpr int Tc = 28;
constexpr int Nc = 1024;
constexpr int Dc = 3;
constexpr int BT = Bc * Tc;       // 112
constexpr int TQ = 128;           // targets per chunk
constexpr int NQ = Nc / TQ;       // 8 chunks

// ws: bestkP [NQ][BT][256] float4 — packed argmin keys (idx in low 10
// mantissa bits), group g holds preds 4g..4g+3. All written before read.

__device__ __forceinline__ float sl1(float d) {
    d = fabsf(d);
    return d < 1.0f ? 0.5f * d * d : d - 0.5f;
}

// key = v with low 10 mantissa bits replaced by the GLOBAL target index.
// fmin over keys == argmin over v truncated to 2^-13 relative; ties -> lowest
// idx for positive keys (jnp first-occurrence); negative-key tie flips are
// within the 2^-13 error budget (R10 measured absmax 0.0).
__device__ __forceinline__ float pack_key(float v, unsigned m) {
    return __uint_as_float((__float_as_uint(v) & 0xFFFFFC00u) | m);
}

// ---------------------------------------------------------------------------
// K1: 896 blocks = 112 bt x 8 chunks, 128 thr (2 waves), 8 preds/thread.
// R10 post-mortem: at P=4 the LDS broadcast pipe (9us/CU) binds over VALU
// (6.7us/SIMD). LDS issues scale 1/P: P=8 at constant 7 waves/CU halves LDS
// to ~4.5us -> VALU-bound. Thread t owns preds 8t..8t+7 (6 float4 loads);
// per 2 targets per pred: 6 fma + 2 v_and_or + 1 v_min3 (4.5 instr/eval).
// Block 0 zeroes out[] (graph edge orders it before K2's atomics).
// ---------------------------------------------------------------------------
__global__ __launch_bounds__(128) void chamfer_kernel(
    const float* __restrict__ X, const float* __restrict__ Tg,
    float4* __restrict__ bestkP, float* __restrict__ out)
{
    __shared__ float4 sT4[TQ];      // 2 KB packed chunk [x,y,z,||t||^2]

    const int bt  = blockIdx.x >> 3;
    const int th  = blockIdx.x & 7;
    const int tid = threadIdx.x;

    if (blockIdx.x == 0 && tid < 2) out[tid] = 0.0f;   // d_out is 0xAA-poisoned

    // ---- stage + pack: thread t packs target th*128+t (one-time, L2-warm) ----
    {
        const float* tg = Tg + (size_t)bt * (Nc * Dc) + th * (TQ * 3);
        const float tx = tg[3 * tid + 0];
        const float ty = tg[3 * tid + 1];
        const float tz = tg[3 * tid + 2];
        sT4[tid] = make_float4(tx, ty, tz, fmaf(tx, tx, fmaf(ty, ty, tz * tz)));
    }

    // ---- preds 8t..8t+7 via six float4 loads (96B lane stride, prologue) ----
    const float4* x4 = (const float4*)(X + (size_t)bt * (Nc * Dc));
    float4 a0 = x4[6 * tid + 0], a1 = x4[6 * tid + 1], a2 = x4[6 * tid + 2];
    float4 a3 = x4[6 * tid + 3], a4 = x4[6 * tid + 4], a5 = x4[6 * tid + 5];
    const float cx[8] = {-2.f * a0.x, -2.f * a0.w, -2.f * a1.z, -2.f * a2.y,
                         -2.f * a3.x, -2.f * a3.w, -2.f * a4.z, -2.f * a5.y};
    const float cy[8] = {-2.f * a0.y, -2.f * a1.x, -2.f * a1.w, -2.f * a2.z,
                         -2.f * a3.y, -2.f * a4.x, -2.f * a4.w, -2.f * a5.z};
    const float cz[8] = {-2.f * a0.z, -2.f * a1.y, -2.f * a2.x, -2.f * a2.w,
                         -2.f * a3.z, -2.f * a4.y, -2.f * a5.x, -2.f * a5.w};
    __syncthreads();

    const unsigned mgBase = (unsigned)(th * TQ);   // global index of chunk start
    float best[8] = {3.4e38f, 3.4e38f, 3.4e38f, 3.4e38f,
                     3.4e38f, 3.4e38f, 3.4e38f, 3.4e38f};

    constexpr int PF = 4;           // register double-buffer depth
    float4 bufA[PF], bufB[PF];
    #pragma unroll
    for (int j = 0; j < PF; ++j) bufA[j] = sT4[j];

    for (int m0 = 0; m0 < TQ; m0 += 2 * PF) {
        #pragma unroll
        for (int j = 0; j < PF; ++j) bufB[j] = sT4[m0 + PF + j];
        #pragma unroll
        for (int j = 0; j < PF; j += 2) {
            const float4 t0 = bufA[j], t1 = bufA[j + 1];
            const unsigned mg0 = mgBase + m0 + j, mg1 = mg0 + 1;
            #pragma unroll
            for (int k = 0; k < 8; ++k) {
                float v0 = fmaf(cx[k], t0.x, fmaf(cy[k], t0.y, fmaf(cz[k], t0.z, t0.w)));
                float v1 = fmaf(cx[k], t1.x, fmaf(cy[k], t1.y, fmaf(cz[k], t1.z, t1.w)));
                best[k] = fminf(fminf(pack_key(v0, mg0), pack_key(v1, mg1)), best[k]);
            }
        }
        #pragma unroll
        for (int j = 0; j < PF; ++j) bufA[j] = sT4[(m0 + 2 * PF + j) & (TQ - 1)];
        #pragma unroll
        for (int j = 0; j < PF; j += 2) {
            const float4 t0 = bufB[j], t1 = bufB[j + 1];
            const unsigned mg0 = mgBase + m0 + PF + j, mg1 = mg0 + 1;
            #pragma unroll
            for (int k = 0; k < 8; ++k) {
                float v0 = fmaf(cx[k], t0.x, fmaf(cy[k], t0.y, fmaf(cz[k], t0.z, t0.w)));
                float v1 = fmaf(cx[k], t1.x, fmaf(cy[k], t1.y, fmaf(cz[k], t1.z, t1.w)));
                best[k] = fminf(fminf(pack_key(v0, mg0), pack_key(v1, mg1)), best[k]);
            }
        }
    }

    // two float4 stores: groups 2t (preds 8t..8t+3) and 2t+1 (8t+4..8t+7)
    const size_t ob = ((size_t)th * BT + bt) * 256 + 2 * tid;
    bestkP[ob]     = make_float4(best[0], best[1], best[2], best[3]);
    bestkP[ob + 1] = make_float4(best[4], best[5], best[6], best[7]);
}

// ---------------------------------------------------------------------------
// K2: 112 blocks (one per bt), 256 thr, 4 preds/thread. Componentwise fmin
// over the 8 chunk keys, extract idx from low 10 bits, gather winning
// targets, smooth-L1, block-reduce, atomicAdd -> out[0]. Each block also
// computes its bt's centroid loss term -> out[1]. out zeroed by K1 block 0.
// ---------------------------------------------------------------------------
__global__ __launch_bounds__(256) void gather_finalize_kernel(
    const float* __restrict__ X, const float* __restrict__ Tg,
    const float* __restrict__ W,
    const float4* __restrict__ bestkP, float* __restrict__ out)
{
    __shared__ float sred[4][8];
    const int bt  = blockIdx.x;
    const int tid = threadIdx.x;
    const size_t rb = (size_t)bt * 256 + tid;

    // ---- combine the 8 chunk keys ----
    float4 bk = bestkP[rb];
    #pragma unroll
    for (int q = 1; q < NQ; ++q) {
        const float4 k2 = bestkP[(size_t)q * BT * 256 + rb];
        bk.x = fminf(bk.x, k2.x);
        bk.y = fminf(bk.y, k2.y);
        bk.z = fminf(bk.z, k2.z);
        bk.w = fminf(bk.w, k2.w);
    }
    const int idx[4] = {
        (int)(__float_as_uint(bk.x) & 1023u),
        (int)(__float_as_uint(bk.y) & 1023u),
        (int)(__float_as_uint(bk.z) & 1023u),
        (int)(__float_as_uint(bk.w) & 1023u)
    };

    // ---- preds + coalesced target block ----
    const float4* x4 = (const float4*)(X + (size_t)bt * (Nc * Dc));
    const float4 a0 = x4[3 * tid + 0];
    const float4 a1 = x4[3 * tid + 1];
    const float4 a2 = x4[3 * tid + 2];
    const float px[4] = {a0.x, a0.w, a1.z, a2.y};
    const float py[4] = {a0.y, a1.x, a1.w, a2.z};
    const float pz[4] = {a0.z, a1.y, a2.x, a2.w};

    const float4* t4 = (const float4*)(Tg + (size_t)bt * (Nc * Dc));
    const float4 r0 = t4[3 * tid + 0];
    const float4 r1 = t4[3 * tid + 1];
    const float4 r2 = t4[3 * tid + 2];

    // ---- gather winners, smooth-L1 ----
    const float* tb = Tg + (size_t)bt * (Nc * Dc);
    float s = 0.0f;
    #pragma unroll
    for (int k = 0; k < 4; ++k) {
        const float tx = tb[idx[k] * 3 + 0];
        const float ty = tb[idx[k] * 3 + 1];
        const float tz = tb[idx[k] * 3 + 2];
        s += sl1(px[k] - tx) + sl1(py[k] - ty) + sl1(pz[k] - tz);
    }

    // ---- 7 block reductions (loss + 3 pred sums + 3 target sums) ----
    float vals[7] = {
        s,
        px[0] + px[1] + px[2] + px[3],
        py[0] + py[1] + py[2] + py[3],
        pz[0] + pz[1] + pz[2] + pz[3],
        r0.x + r0.w + r1.z + r2.y,
        r0.y + r1.x + r1.w + r2.z,
        r0.z + r1.y + r2.x + r2.w
    };
    const int lane = tid & 63, wid = tid >> 6;
    #pragma unroll
    for (int k = 0; k < 7; ++k) {
        float v = vals[k];
        #pragma unroll
        for (int off = 32; off; off >>= 1) v += __shfl_down(v, off, 64);
        if (lane == 0) sred[wid][k] = v;
    }
    __syncthreads();
    if (tid == 0) {
        float tot[7];
        #pragma unroll
        for (int k = 0; k < 7; ++k)
            tot[k] = sred[0][k] + sred[1][k] + sred[2][k] + sred[3][k];
        // loss contribution: w_bt * (sl1 sum / (N*D)) / B
        atomicAdd(out, tot[0] * W[bt] * (1.0f / (Nc * Dc)) * (1.0f / Bc));
        // centroid contribution for this bt
        const float inv = 1.0f / Nc;
        float lc = sl1((tot[1] - tot[4]) * inv)
                 + sl1((tot[2] - tot[5]) * inv)
                 + sl1((tot[3] - tot[6]) * inv);
        atomicAdd(out + 1, lc * (1.0f / (Bc * Dc)));   // lossc = sum / (B*3)
    }
}

extern "C" void kernel_launch(void* const* d_in, const int* in_sizes, int n_in,
                              void* d_out, int out_size, void* d_ws, size_t ws_size,
                              hipStream_t stream) {
    const float* X  = (const float*)d_in[0];  // X_v        [4,28,1024,3]
    const float* Tg = (const float*)d_in[1];  // target_X_v [4,28,1024,3]
    const float* W  = (const float*)d_in[2];  // weights    [4,28]
    float* out = (float*)d_out;               // {loss, lossc}

    float4* bestkP = (float4*)d_ws;           // [NQ*BT*256] packed key groups

    chamfer_kernel<<<BT * NQ, 128, 0, stream>>>(X, Tg, bestkP, out);
    gather_finalize_kernel<<<BT, 256, 0, stream>>>(X, Tg, W, bestkP, out);
}